// Round 8
// baseline (288.086 us; speedup 1.0000x reference)
//
#include <hip/hip_runtime.h>
#include <cstdint>
#include <cstddef>

// Problem constants
#define B_    8
#define C_    256
#define H_    64
#define W_    64
#define A_    4
#define NH_   8
#define DH_   32
#define L_    1024
#define NPAIR 32
#define QKVN  768

typedef __bf16 bf16;
typedef __bf16 bf16x8 __attribute__((ext_vector_type(8)));
typedef __bf16 bf16x4 __attribute__((ext_vector_type(4)));
typedef float  f32x4  __attribute__((ext_vector_type(4)));

// dh^-0.5 * log2(e): folded into Q at projection time
#define QSCALE 0.25506866729736328f

__device__ inline f32x4 mfma16(bf16x8 a, bf16x8 b, f32x4 c) {
    return __builtin_amdgcn_mfma_f32_16x16x32_bf16(a, b, c, 0, 0, 0);
}
__device__ inline bf16x8 ld8(const bf16* p) { return *(const bf16x8*)p; }

// async global->LDS, 16B per lane; LDS dest = wave-uniform base + lane*16
__device__ inline void stage16(const bf16* g, bf16* l) {
    __builtin_amdgcn_global_load_lds(
        (const __attribute__((address_space(1))) void*)g,
        (__attribute__((address_space(3))) void*)l, 16, 0, 0);
}

// ---------------------------------------------------------------------------
// K0: fused  (a) x[B,C,H,W] f32 -> xa[pair,l,c] bf16   [blocks 0..1023]
//            (b) W_in/W_out f32 -> bf16 convert        [blocks 1024..2047]
// ---------------------------------------------------------------------------
#define NW4 (786432 / 4)
#define NO4 (262144 / 4)
__global__ __launch_bounds__(256) void k_split(const float* __restrict__ x,
                                               bf16* __restrict__ xa,
                                               const float* __restrict__ Win,
                                               const float* __restrict__ Wout,
                                               bf16* __restrict__ Winb,
                                               bf16* __restrict__ Woutb) {
    __shared__ float lds[32][257];
    int bid = blockIdx.x;
    int t = threadIdx.x;
    if (bid >= NPAIR * 32) {
        int tid = (bid - NPAIR * 32) * 256 + t;
        if (tid < NW4) {
            float4 v = ((const float4*)Win)[tid];
            bf16x4 ov = {(bf16)v.x, (bf16)v.y, (bf16)v.z, (bf16)v.w};
            ((bf16x4*)Winb)[tid] = ov;
        } else if (tid < NW4 + NO4) {
            int t2 = tid - NW4;
            float4 v = ((const float4*)Wout)[t2];
            bf16x4 ov = {(bf16)v.x, (bf16)v.y, (bf16)v.z, (bf16)v.w};
            ((bf16x4*)Woutb)[t2] = ov;
        }
        return;
    }
    int pair = bid >> 5, p = bid & 31;
    int b = pair >> 2, a = pair & 3, i = a >> 1, j = a & 1;
    int q = t & 31, csub = t >> 5;
    const float* xb = x + (size_t)b * C_ * H_ * W_ + (size_t)(i * 32 + p) * W_ + j * 32;
    for (int r = 0; r < 32; ++r) {
        int c = r * 8 + csub;
        lds[q][c] = xb[(size_t)c * H_ * W_ + q];
    }
    __syncthreads();
    bf16* xr = xa + ((size_t)pair * L_ + (size_t)p * 32) * C_;
    for (int r = 0; r < 32; ++r) {
        xr[(size_t)r * C_ + t] = (bf16)lds[r][t];
    }
}

// ---------------------------------------------------------------------------
// K1: in-projection, m97-style LDS-staged GEMM.
// Tile 128(M) x 128(N), BK=64, 4 waves 2x2, each wave 64x64 (4x4 frags).
// Epilogue: Q cols (<256) prescaled -> qk, K cols -> qk, V cols -> vT.
// grid: 32 pair x 8 mt x 6 nt = 1536
// ---------------------------------------------------------------------------
__global__ __launch_bounds__(256) void k_qkv(const bf16* __restrict__ xa,
                                             const bf16* __restrict__ Win,
                                             const float* __restrict__ bin,
                                             bf16* __restrict__ qk,
                                             bf16* __restrict__ vT) {
    __shared__ __align__(16) bf16 lA[128 * 64];
    __shared__ __align__(16) bf16 lB[128 * 64];
    int bid = blockIdx.x;
    int nt = bid % 6, mt = (bid / 6) & 7, pair = bid / 48;
    int a = pair & 3;
    int t = threadIdx.x, w = t >> 6, lane = t & 63;
    int wm = w >> 1, wn = w & 1;
    int quad = lane >> 4, l16 = lane & 15;
    int m0 = mt * 128, n0 = nt * 128;
    int r8 = lane >> 3, pc = lane & 7, jj = pc ^ r8;
    const bf16* ga = xa + (size_t)pair * L_ * C_ + (size_t)(m0 + w * 32 + r8) * C_ + jj * 8;
    const bf16* gb = Win + (size_t)a * QKVN * C_ + (size_t)(n0 + w * 32 + r8) * C_ + jj * 8;
    f32x4 acc[4][4];
#pragma unroll
    for (int fm = 0; fm < 4; ++fm)
#pragma unroll
        for (int fn = 0; fn < 4; ++fn) acc[fm][fn] = (f32x4){0.f, 0.f, 0.f, 0.f};
    for (int k0 = 0; k0 < C_; k0 += 64) {
        __syncthreads();
#pragma unroll
        for (int i = 0; i < 4; ++i) {
            stage16(ga + (size_t)(i * 8) * C_ + k0, lA + (w * 32 + i * 8) * 64);
            stage16(gb + (size_t)(i * 8) * C_ + k0, lB + (w * 32 + i * 8) * 64);
        }
        __syncthreads();
#pragma unroll
        for (int ks = 0; ks < 2; ++ks) {
            int p = (ks * 4 + quad) ^ (l16 & 7);
            bf16x8 am[4], bn[4];
#pragma unroll
            for (int f = 0; f < 4; ++f) {
                am[f] = *(const bf16x8*)&lA[(wm * 64 + f * 16 + l16) * 64 + p * 8];
                bn[f] = *(const bf16x8*)&lB[(wn * 64 + f * 16 + l16) * 64 + p * 8];
            }
#pragma unroll
            for (int fm = 0; fm < 4; ++fm)
#pragma unroll
                for (int fn = 0; fn < 4; ++fn)
                    acc[fm][fn] = mfma16(am[fm], bn[fn], acc[fm][fn]);
        }
    }
    int colbase = n0 + wn * 64;
    int mb = m0 + wm * 64;
    if (colbase < 512) {
        float sc = (colbase < 256) ? QSCALE : 1.0f;
        bf16* ob = qk + (size_t)pair * L_ * 512;
#pragma unroll
        for (int fn = 0; fn < 4; ++fn) {
            int col = colbase + fn * 16 + l16;
            float bias = bin[a * QKVN + col];
#pragma unroll
            for (int fm = 0; fm < 4; ++fm) {
                int m = mb + fm * 16 + quad * 4;
#pragma unroll
                for (int r = 0; r < 4; ++r)
                    ob[(size_t)(m + r) * 512 + col] = (bf16)((acc[fm][fn][r] + bias) * sc);
            }
        }
    } else {
        bf16* vb = vT + (size_t)pair * C_ * L_;
#pragma unroll
        for (int fn = 0; fn < 4; ++fn) {
            int e = colbase - 512 + fn * 16 + l16;
            float bias = bin[a * QKVN + colbase + fn * 16 + l16];
#pragma unroll
            for (int fm = 0; fm < 4; ++fm) {
                int m = mb + fm * 16 + quad * 4;
                bf16x4 pk = {(bf16)(acc[fm][fn][0] + bias), (bf16)(acc[fm][fn][1] + bias),
                             (bf16)(acc[fm][fn][2] + bias), (bf16)(acc[fm][fn][3] + bias)};
                *(bf16x4*)&vb[(size_t)e * L_ + m] = pk;
            }
        }
    }
}

// ---------------------------------------------------------------------------
// K2: attention. block 256 = 4 independent waves (no __syncthreads).
// Each wave: 2 Q-frags (32 q-rows) of one (pair, head) -> 8192 waves total
// (32/CU) for occupancy; LDS 18.4 KB/block so 8 blocks/CU fit.
// Q pre-scaled so p = exp2(s), via raw v_exp_f32 (__builtin_amdgcn_exp2f) --
// scores are bounded, no ocml overflow path needed.
// K-frag rows loaded as kv = l16*4 + kb -> after exp each lane holds 4
// consecutive P-columns per r -> single ds_write_b64; LDS phys col == kv.
// grid: pair = bid&31, head = (bid>>5)&7, qb = bid>>8 (0..7).
// ---------------------------------------------------------------------------
__global__ __launch_bounds__(256) void k_attn(const bf16* __restrict__ qk,
                                              const bf16* __restrict__ vT,
                                              bf16* __restrict__ o) {
    __shared__ __align__(16) bf16 pl[4][2][16 * 72];  // [wave][frag][row*72+col]
    int bid = blockIdx.x;
    int pair = bid & 31, rest = bid >> 5;
    int head = rest & 7, qb = rest >> 3;  // qb 0..7
    int t = threadIdx.x, w = t >> 6, lane = t & 63, quad = lane >> 4, l16 = lane & 15;
    const bf16* qbp  = qk + (size_t)pair * L_ * 512;
    const bf16* kptr = qbp + 256 + head * DH_ + quad * 8;
    const bf16* vt0  = vT + ((size_t)pair * C_ + head * DH_) * L_;
    int qbase = qb * 128 + w * 32;
    bf16x8 qf[2];
    f32x4 acc0[2], acc1[2], l4[2];
#pragma unroll
    for (int f = 0; f < 2; ++f) {
        qf[f] = ld8(qbp + (size_t)(qbase + f * 16 + l16) * 512 + head * DH_ + quad * 8);
        acc0[f] = (f32x4){0.f, 0.f, 0.f, 0.f};
        acc1[f] = (f32x4){0.f, 0.f, 0.f, 0.f};
        l4[f]   = (f32x4){0.f, 0.f, 0.f, 0.f};
    }
    for (int kv0 = 0; kv0 < L_; kv0 += 64) {
        bf16x8 kf[4], vf[4];
#pragma unroll
        for (int kb = 0; kb < 4; ++kb)
            kf[kb] = ld8(kptr + (size_t)(kv0 + l16 * 4 + kb) * 512);
#pragma unroll
        for (int ks = 0; ks < 2; ++ks) {
            vf[ks * 2 + 0] = ld8(vt0 + (size_t)l16 * L_ + kv0 + ks * 32 + quad * 8);
            vf[ks * 2 + 1] = ld8(vt0 + (size_t)(16 + l16) * L_ + kv0 + ks * 32 + quad * 8);
        }
#pragma unroll
        for (int f = 0; f < 2; ++f) {
            f32x4 s[4];
#pragma unroll
            for (int kb = 0; kb < 4; ++kb) s[kb] = mfma16(qf[f], kf[kb], (f32x4){0.f, 0.f, 0.f, 0.f});
            bf16* pw = &pl[w][f][0];
#pragma unroll
            for (int r = 0; r < 4; ++r) {
                float p0 = __builtin_amdgcn_exp2f(s[0][r]);
                float p1 = __builtin_amdgcn_exp2f(s[1][r]);
                float p2 = __builtin_amdgcn_exp2f(s[2][r]);
                float p3 = __builtin_amdgcn_exp2f(s[3][r]);
                l4[f][r] += (p0 + p1) + (p2 + p3);
                bf16x4 pv = {(bf16)p0, (bf16)p1, (bf16)p2, (bf16)p3};
                *(bf16x4*)&pw[(quad * 4 + r) * 72 + l16 * 4] = pv;
            }
#pragma unroll
            for (int ks = 0; ks < 2; ++ks) {
                bf16x8 pf = *(const bf16x8*)&pw[l16 * 72 + ks * 32 + quad * 8];
                acc0[f] = mfma16(pf, vf[ks * 2 + 0], acc0[f]);
                acc1[f] = mfma16(pf, vf[ks * 2 + 1], acc1[f]);
            }
        }
    }
    bf16* orow = o + (size_t)pair * L_ * C_ + head * DH_;
#pragma unroll
    for (int f = 0; f < 2; ++f) {
#pragma unroll
        for (int r = 0; r < 4; ++r) {
            float s1 = l4[f][r];
#pragma unroll
            for (int off = 1; off < 16; off <<= 1) s1 += __shfl_xor(s1, off);
            float inv = 1.f / s1;
            int row = qbase + f * 16 + quad * 4 + r;
            orow[(size_t)row * C_ + l16]      = (bf16)(acc0[f][r] * inv);
            orow[(size_t)row * C_ + 16 + l16] = (bf16)(acc1[f][r] * inv);
        }
    }
}

// ---------------------------------------------------------------------------
// K3: y = LayerNorm(o @ W_out[a]^T + b_out[a] + xa) * gamma + beta  (bf16 out)
// m97-style staged GEMM: tile 128(M) x 256(N=full), BK=64, 4 waves 2x2,
// each wave 64x128 (4x8 frags). LN: shfl partials + LDS cross-wave combine.
// grid: 32 pair x 8 mt = 256
// ---------------------------------------------------------------------------
__global__ __launch_bounds__(256) void k_out(const bf16* __restrict__ o,
                                             const bf16* __restrict__ Wout,
                                             const float* __restrict__ bout,
                                             const bf16* __restrict__ xa,
                                             const float* __restrict__ gamma,
                                             const float* __restrict__ beta,
                                             bf16* __restrict__ y) {
    __shared__ __align__(16) bf16 lA[128 * 64];
    __shared__ __align__(16) bf16 lB[256 * 64];
    __shared__ float red[2][2][64][2];
    int bid = blockIdx.x;
    int mt = bid & 7, pair = bid >> 3;
    int a = pair & 3;
    int t = threadIdx.x, w = t >> 6, lane = t & 63;
    int wm = w >> 1, wn = w & 1;
    int quad = lane >> 4, l16 = lane & 15;
    int m0 = mt * 128;
    int r8 = lane >> 3, pc = lane & 7, jj = pc ^ r8;
    const bf16* ga = o + (size_t)pair * L_ * C_ + (size_t)(m0 + w * 32 + r8) * C_ + jj * 8;
    const bf16* gb = Wout + (size_t)a * C_ * C_ + (size_t)(w * 64 + r8) * C_ + jj * 8;
    f32x4 acc[4][8];
#pragma unroll
    for (int fm = 0; fm < 4; ++fm)
#pragma unroll
        for (int fn = 0; fn < 8; ++fn) acc[fm][fn] = (f32x4){0.f, 0.f, 0.f, 0.f};
    for (int k0 = 0; k0 < C_; k0 += 64) {
        __syncthreads();
#pragma unroll
        for (int i = 0; i < 4; ++i)
            stage16(ga + (size_t)(i * 8) * C_ + k0, lA + (w * 32 + i * 8) * 64);
#pragma unroll
        for (int i = 0; i < 8; ++i)
            stage16(gb + (size_t)(i * 8) * C_ + k0, lB + (w * 64 + i * 8) * 64);
        __syncthreads();
#pragma unroll
        for (int ks = 0; ks < 2; ++ks) {
            int p = (ks * 4 + quad) ^ (l16 & 7);
            bf16x8 am[4], bn[8];
#pragma unroll
            for (int f = 0; f < 4; ++f)
                am[f] = *(const bf16x8*)&lA[(wm * 64 + f * 16 + l16) * 64 + p * 8];
#pragma unroll
            for (int f = 0; f < 8; ++f)
                bn[f] = *(const bf16x8*)&lB[(wn * 128 + f * 16 + l16) * 64 + p * 8];
#pragma unroll
            for (int fm = 0; fm < 4; ++fm)
#pragma unroll
                for (int fn = 0; fn < 8; ++fn)
                    acc[fm][fn] = mfma16(am[fm], bn[fn], acc[fm][fn]);
        }
    }
    // bias + residual into acc
    const bf16* xb = xa + ((size_t)pair * L_ + m0 + wm * 64) * C_;
#pragma unroll
    for (int fn = 0; fn < 8; ++fn) {
        int col = wn * 128 + fn * 16 + l16;
        float bias = bout[a * C_ + col];
#pragma unroll
        for (int fm = 0; fm < 4; ++fm)
#pragma unroll
            for (int r = 0; r < 4; ++r)
                acc[fm][fn][r] += bias + (float)xb[(size_t)(fm * 16 + quad * 4 + r) * C_ + col];
    }
    // per-wave partial row sums -> LDS
#pragma unroll
    for (int fm = 0; fm < 4; ++fm) {
#pragma unroll
        for (int r = 0; r < 4; ++r) {
            float s1 = 0.f, s2 = 0.f;
#pragma unroll
            for (int fn = 0; fn < 8; ++fn) {
                float v = acc[fm][fn][r];
                s1 += v; s2 += v * v;
            }
#pragma unroll
            for (int off = 1; off < 16; off <<= 1) {
                s1 += __shfl_xor(s1, off);
                s2 += __shfl_xor(s2, off);
            }
            if (l16 == 0) {
                int rl = fm * 16 + quad * 4 + r;
                red[wm][wn][rl][0] = s1;
                red[wm][wn][rl][1] = s2;
            }
        }
    }
    __syncthreads();
    bf16* yb = y + ((size_t)pair * L_ + m0 + wm * 64) * C_;
#pragma unroll
    for (int fm = 0; fm < 4; ++fm) {
#pragma unroll
        for (int r = 0; r < 4; ++r) {
            int rl = fm * 16 + quad * 4 + r;
            float t1 = red[wm][0][rl][0] + red[wm][1][rl][0];
            float t2 = red[wm][0][rl][1] + red[wm][1][rl][1];
            float mu = t1 * (1.f / 256.f);
            float var = t2 * (1.f / 256.f) - mu * mu;
            float rstd = rsqrtf(var + 1e-5f);
#pragma unroll
            for (int fn = 0; fn < 8; ++fn) {
                int col = wn * 128 + fn * 16 + l16;
                yb[(size_t)rl * C_ + col] =
                    (bf16)((acc[fm][fn][r] - mu) * rstd * gamma[col] + beta[col]);
            }
        }
    }
}

// ---------------------------------------------------------------------------
// K4: y[pair, l, c] (bf16) -> out[B,C,H,W] (f32)
// ---------------------------------------------------------------------------
__global__ __launch_bounds__(256) void k_merge(const bf16* __restrict__ y,
                                               float* __restrict__ out) {
    __shared__ float lds[32][257];
    int bid = blockIdx.x;
    int pair = bid >> 5, p = bid & 31;
    int b = pair >> 2, a = pair & 3, i = a >> 1, j = a & 1;
    int t = threadIdx.x;
    int q = t & 31, csub = t >> 5;
    const bf16* yr = y + ((size_t)pair * L_ + (size_t)p * 32) * C_;
    for (int r = 0; r < 32; ++r) {
        lds[r][t] = (float)yr[(size_t)r * C_ + t];
    }
    __syncthreads();
    float* xb = out + (size_t)b * C_ * H_ * W_ + (size_t)(i * 32 + p) * W_ + j * 32;
    for (int r = 0; r < 32; ++r) {
        int c = r * 8 + csub;
        xb[(size_t)c * H_ * W_ + q] = lds[q][c];
    }
}

// ---------------------------------------------------------------------------
extern "C" void kernel_launch(void* const* d_in, const int* in_sizes, int n_in,
                              void* d_out, int out_size, void* d_ws, size_t ws_size,
                              hipStream_t stream) {
    (void)in_sizes; (void)n_in; (void)out_size; (void)ws_size;
    const float* x     = (const float*)d_in[0];
    const float* Win   = (const float*)d_in[1];
    const float* bin   = (const float*)d_in[2];
    const float* Wout  = (const float*)d_in[3];
    const float* bout  = (const float*)d_in[4];
    const float* gamma = (const float*)d_in[5];
    const float* beta  = (const float*)d_in[6];
    float* out = (float*)d_out;

    char* ws = (char*)d_ws;
    bf16* xa    = (bf16*)ws;                           // 16 MiB
    bf16* qk    = (bf16*)(ws + ((size_t)16 << 20));    // 32 MiB  [pair][L][512]
    bf16* vT    = (bf16*)(ws + ((size_t)48 << 20));    // 16 MiB  [pair][256][1024]
    bf16* o     = (bf16*)(ws + ((size_t)64 << 20));    // 16 MiB
    bf16* Winb  = (bf16*)(ws + ((size_t)80 << 20));    // 1.5 MiB
    bf16* Woutb = (bf16*)(ws + ((size_t)82 << 20));    // 0.5 MiB
    bf16* y     = (bf16*)(ws + ((size_t)16 << 20));    // 16 MiB, aliases dead qk

    k_split<<<NPAIR * 32 + 1024, 256, 0, stream>>>(x, xa, Win, Wout, Winb, Woutb);
    k_qkv<<<NPAIR * 8 * 6, 256, 0, stream>>>(xa, Winb, bin, qk, vT);
    k_attn<<<NPAIR * NH_ * 8, 256, 0, stream>>>(qk, vT, o);
    k_out<<<NPAIR * 8, 256, 0, stream>>>(o, Woutb, bout, xa, gamma, beta, y);
    k_merge<<<NPAIR * 32, 256, 0, stream>>>(y, out);
}

// Round 9
// 225.791 us; speedup vs baseline: 1.2759x; 1.2759x over previous
//
#include <hip/hip_runtime.h>
#include <cstdint>
#include <cstddef>

// Problem constants
#define B_    8
#define C_    256
#define H_    64
#define W_    64
#define A_    4
#define NH_   8
#define DH_   32
#define L_    1024
#define NPAIR 32
#define QKVN  768

typedef __bf16 bf16;
typedef __bf16 bf16x8 __attribute__((ext_vector_type(8)));
typedef __bf16 bf16x4 __attribute__((ext_vector_type(4)));
typedef float  f32x4  __attribute__((ext_vector_type(4)));

// dh^-0.5 * log2(e): folded into Q at projection time
#define QSCALE 0.25506866729736328f

__device__ inline f32x4 mfma16(bf16x8 a, bf16x8 b, f32x4 c) {
    return __builtin_amdgcn_mfma_f32_16x16x32_bf16(a, b, c, 0, 0, 0);
}
__device__ inline bf16x8 ld8(const bf16* p) { return *(const bf16x8*)p; }

// async global->LDS, 16B per lane; LDS dest = wave-uniform base + lane*16
__device__ inline void stage16(const bf16* g, bf16* l) {
    __builtin_amdgcn_global_load_lds(
        (const __attribute__((address_space(1))) void*)g,
        (__attribute__((address_space(3))) void*)l, 16, 0, 0);
}

// ---------------------------------------------------------------------------
// K0: fused  (a) x[B,C,H,W] f32 -> xa[pair,l,c] bf16   [blocks 0..1023]
//            (b) W_in/W_out f32 -> bf16 convert        [blocks 1024..2047]
// ---------------------------------------------------------------------------
#define NW4 (786432 / 4)
#define NO4 (262144 / 4)
__global__ __launch_bounds__(256) void k_split(const float* __restrict__ x,
                                               bf16* __restrict__ xa,
                                               const float* __restrict__ Win,
                                               const float* __restrict__ Wout,
                                               bf16* __restrict__ Winb,
                                               bf16* __restrict__ Woutb) {
    __shared__ float lds[32][257];
    int bid = blockIdx.x;
    int t = threadIdx.x;
    if (bid >= NPAIR * 32) {
        int tid = (bid - NPAIR * 32) * 256 + t;
        if (tid < NW4) {
            float4 v = ((const float4*)Win)[tid];
            bf16x4 ov = {(bf16)v.x, (bf16)v.y, (bf16)v.z, (bf16)v.w};
            ((bf16x4*)Winb)[tid] = ov;
        } else if (tid < NW4 + NO4) {
            int t2 = tid - NW4;
            float4 v = ((const float4*)Wout)[t2];
            bf16x4 ov = {(bf16)v.x, (bf16)v.y, (bf16)v.z, (bf16)v.w};
            ((bf16x4*)Woutb)[t2] = ov;
        }
        return;
    }
    int pair = bid >> 5, p = bid & 31;
    int b = pair >> 2, a = pair & 3, i = a >> 1, j = a & 1;
    int q = t & 31, csub = t >> 5;
    const float* xb = x + (size_t)b * C_ * H_ * W_ + (size_t)(i * 32 + p) * W_ + j * 32;
    for (int r = 0; r < 32; ++r) {
        int c = r * 8 + csub;
        lds[q][c] = xb[(size_t)c * H_ * W_ + q];
    }
    __syncthreads();
    bf16* xr = xa + ((size_t)pair * L_ + (size_t)p * 32) * C_;
    for (int r = 0; r < 32; ++r) {
        xr[(size_t)r * C_ + t] = (bf16)lds[r][t];
    }
}

// ---------------------------------------------------------------------------
// K1: in-projection, m97-style LDS-staged GEMM.
// Tile 128(M) x 128(N), BK=64, 4 waves 2x2, each wave 64x64 (4x4 frags).
// Epilogue: Q cols (<256) prescaled -> qk, K cols -> qk, V cols -> vT.
// grid: 32 pair x 8 mt x 6 nt = 1536
// ---------------------------------------------------------------------------
__global__ __launch_bounds__(256) void k_qkv(const bf16* __restrict__ xa,
                                             const bf16* __restrict__ Win,
                                             const float* __restrict__ bin,
                                             bf16* __restrict__ qk,
                                             bf16* __restrict__ vT) {
    __shared__ __align__(16) bf16 lA[128 * 64];
    __shared__ __align__(16) bf16 lB[128 * 64];
    int bid = blockIdx.x;
    int nt = bid % 6, mt = (bid / 6) & 7, pair = bid / 48;
    int a = pair & 3;
    int t = threadIdx.x, w = t >> 6, lane = t & 63;
    int wm = w >> 1, wn = w & 1;
    int quad = lane >> 4, l16 = lane & 15;
    int m0 = mt * 128, n0 = nt * 128;
    int r8 = lane >> 3, pc = lane & 7, jj = pc ^ r8;
    const bf16* ga = xa + (size_t)pair * L_ * C_ + (size_t)(m0 + w * 32 + r8) * C_ + jj * 8;
    const bf16* gb = Win + (size_t)a * QKVN * C_ + (size_t)(n0 + w * 32 + r8) * C_ + jj * 8;
    f32x4 acc[4][4];
#pragma unroll
    for (int fm = 0; fm < 4; ++fm)
#pragma unroll
        for (int fn = 0; fn < 4; ++fn) acc[fm][fn] = (f32x4){0.f, 0.f, 0.f, 0.f};
    for (int k0 = 0; k0 < C_; k0 += 64) {
        __syncthreads();
#pragma unroll
        for (int i = 0; i < 4; ++i) {
            stage16(ga + (size_t)(i * 8) * C_ + k0, lA + (w * 32 + i * 8) * 64);
            stage16(gb + (size_t)(i * 8) * C_ + k0, lB + (w * 32 + i * 8) * 64);
        }
        __syncthreads();
#pragma unroll
        for (int ks = 0; ks < 2; ++ks) {
            int p = (ks * 4 + quad) ^ (l16 & 7);
            bf16x8 am[4], bn[4];
#pragma unroll
            for (int f = 0; f < 4; ++f) {
                am[f] = *(const bf16x8*)&lA[(wm * 64 + f * 16 + l16) * 64 + p * 8];
                bn[f] = *(const bf16x8*)&lB[(wn * 64 + f * 16 + l16) * 64 + p * 8];
            }
#pragma unroll
            for (int fm = 0; fm < 4; ++fm)
#pragma unroll
                for (int fn = 0; fn < 4; ++fn)
                    acc[fm][fn] = mfma16(am[fm], bn[fn], acc[fm][fn]);
        }
    }
    int colbase = n0 + wn * 64;
    int mb = m0 + wm * 64;
    if (colbase < 512) {
        float sc = (colbase < 256) ? QSCALE : 1.0f;
        bf16* ob = qk + (size_t)pair * L_ * 512;
#pragma unroll
        for (int fn = 0; fn < 4; ++fn) {
            int col = colbase + fn * 16 + l16;
            float bias = bin[a * QKVN + col];
#pragma unroll
            for (int fm = 0; fm < 4; ++fm) {
                int m = mb + fm * 16 + quad * 4;
#pragma unroll
                for (int r = 0; r < 4; ++r)
                    ob[(size_t)(m + r) * 512 + col] = (bf16)((acc[fm][fn][r] + bias) * sc);
            }
        }
    } else {
        bf16* vb = vT + (size_t)pair * C_ * L_;
#pragma unroll
        for (int fn = 0; fn < 4; ++fn) {
            int e = colbase - 512 + fn * 16 + l16;
            float bias = bin[a * QKVN + colbase + fn * 16 + l16];
#pragma unroll
            for (int fm = 0; fm < 4; ++fm) {
                int m = mb + fm * 16 + quad * 4;
                bf16x4 pk = {(bf16)(acc[fm][fn][0] + bias), (bf16)(acc[fm][fn][1] + bias),
                             (bf16)(acc[fm][fn][2] + bias), (bf16)(acc[fm][fn][3] + bias)};
                *(bf16x4*)&vb[(size_t)e * L_ + m] = pk;
            }
        }
    }
}

// ---------------------------------------------------------------------------
// K2: attention. block 256 = 4 independent waves (no __syncthreads).
// R7 structure (4 Q-frags/wave, 64 q-rows, K/V loads amortized 4x) +
// raw v_exp_f32 via __builtin_amdgcn_exp2f (scores bounded; validated R8).
// K-frag rows loaded as kv = l16*4 + kb -> after exp each lane holds 4
// consecutive P-columns per r -> single ds_write_b64; LDS phys col == kv.
// grid: pair = bid&31, head = (bid>>5)&7, qb = bid>>8 (0..3). 1024 blocks.
// ---------------------------------------------------------------------------
__global__ __launch_bounds__(256) void k_attn(const bf16* __restrict__ qk,
                                              const bf16* __restrict__ vT,
                                              bf16* __restrict__ o) {
    __shared__ __align__(16) bf16 pl[4][4][16 * 72];  // [wave][frag][row*72+col]
    int bid = blockIdx.x;
    int pair = bid & 31, rest = bid >> 5;
    int head = rest & 7, qb = rest >> 3;  // qb 0..3
    int t = threadIdx.x, w = t >> 6, lane = t & 63, quad = lane >> 4, l16 = lane & 15;
    const bf16* qbp  = qk + (size_t)pair * L_ * 512;
    const bf16* kptr = qbp + 256 + head * DH_ + quad * 8;
    const bf16* vt0  = vT + ((size_t)pair * C_ + head * DH_) * L_;
    int qbase = qb * 256 + w * 64;
    bf16x8 qf[4];
    f32x4 acc0[4], acc1[4], l4[4];
#pragma unroll
    for (int f = 0; f < 4; ++f) {
        qf[f] = ld8(qbp + (size_t)(qbase + f * 16 + l16) * 512 + head * DH_ + quad * 8);
        acc0[f] = (f32x4){0.f, 0.f, 0.f, 0.f};
        acc1[f] = (f32x4){0.f, 0.f, 0.f, 0.f};
        l4[f]   = (f32x4){0.f, 0.f, 0.f, 0.f};
    }
    for (int kv0 = 0; kv0 < L_; kv0 += 64) {
        bf16x8 kf[4], vf[4];
#pragma unroll
        for (int kb = 0; kb < 4; ++kb)
            kf[kb] = ld8(kptr + (size_t)(kv0 + l16 * 4 + kb) * 512);
#pragma unroll
        for (int ks = 0; ks < 2; ++ks) {
            vf[ks * 2 + 0] = ld8(vt0 + (size_t)l16 * L_ + kv0 + ks * 32 + quad * 8);
            vf[ks * 2 + 1] = ld8(vt0 + (size_t)(16 + l16) * L_ + kv0 + ks * 32 + quad * 8);
        }
#pragma unroll
        for (int f = 0; f < 4; ++f) {
            f32x4 s[4];
#pragma unroll
            for (int kb = 0; kb < 4; ++kb) s[kb] = mfma16(qf[f], kf[kb], (f32x4){0.f, 0.f, 0.f, 0.f});
            bf16* pw = &pl[w][f][0];
#pragma unroll
            for (int r = 0; r < 4; ++r) {
                float p0 = __builtin_amdgcn_exp2f(s[0][r]);
                float p1 = __builtin_amdgcn_exp2f(s[1][r]);
                float p2 = __builtin_amdgcn_exp2f(s[2][r]);
                float p3 = __builtin_amdgcn_exp2f(s[3][r]);
                l4[f][r] += (p0 + p1) + (p2 + p3);
                bf16x4 pv = {(bf16)p0, (bf16)p1, (bf16)p2, (bf16)p3};
                *(bf16x4*)&pw[(quad * 4 + r) * 72 + l16 * 4] = pv;
            }
#pragma unroll
            for (int ks = 0; ks < 2; ++ks) {
                bf16x8 pf = *(const bf16x8*)&pw[l16 * 72 + ks * 32 + quad * 8];
                acc0[f] = mfma16(pf, vf[ks * 2 + 0], acc0[f]);
                acc1[f] = mfma16(pf, vf[ks * 2 + 1], acc1[f]);
            }
        }
    }
    bf16* orow = o + (size_t)pair * L_ * C_ + head * DH_;
#pragma unroll
    for (int f = 0; f < 4; ++f) {
#pragma unroll
        for (int r = 0; r < 4; ++r) {
            float s1 = l4[f][r];
#pragma unroll
            for (int off = 1; off < 16; off <<= 1) s1 += __shfl_xor(s1, off);
            float inv = 1.f / s1;
            int row = qbase + f * 16 + quad * 4 + r;
            orow[(size_t)row * C_ + l16]      = (bf16)(acc0[f][r] * inv);
            orow[(size_t)row * C_ + 16 + l16] = (bf16)(acc1[f][r] * inv);
        }
    }
}

// ---------------------------------------------------------------------------
// K3: y = LayerNorm(o @ W_out[a]^T + b_out[a] + xa) * gamma + beta  (bf16 out)
// m97-style staged GEMM: tile 128(M) x 256(N=full), BK=64, 4 waves 2x2,
// each wave 64x128 (4x8 frags). LN: shfl partials + LDS cross-wave combine.
// grid: 32 pair x 8 mt = 256
// ---------------------------------------------------------------------------
__global__ __launch_bounds__(256) void k_out(const bf16* __restrict__ o,
                                             const bf16* __restrict__ Wout,
                                             const float* __restrict__ bout,
                                             const bf16* __restrict__ xa,
                                             const float* __restrict__ gamma,
                                             const float* __restrict__ beta,
                                             bf16* __restrict__ y) {
    __shared__ __align__(16) bf16 lA[128 * 64];
    __shared__ __align__(16) bf16 lB[256 * 64];
    __shared__ float red[2][2][64][2];
    int bid = blockIdx.x;
    int mt = bid & 7, pair = bid >> 3;
    int a = pair & 3;
    int t = threadIdx.x, w = t >> 6, lane = t & 63;
    int wm = w >> 1, wn = w & 1;
    int quad = lane >> 4, l16 = lane & 15;
    int m0 = mt * 128;
    int r8 = lane >> 3, pc = lane & 7, jj = pc ^ r8;
    const bf16* ga = o + (size_t)pair * L_ * C_ + (size_t)(m0 + w * 32 + r8) * C_ + jj * 8;
    const bf16* gb = Wout + (size_t)a * C_ * C_ + (size_t)(w * 64 + r8) * C_ + jj * 8;
    f32x4 acc[4][8];
#pragma unroll
    for (int fm = 0; fm < 4; ++fm)
#pragma unroll
        for (int fn = 0; fn < 8; ++fn) acc[fm][fn] = (f32x4){0.f, 0.f, 0.f, 0.f};
    for (int k0 = 0; k0 < C_; k0 += 64) {
        __syncthreads();
#pragma unroll
        for (int i = 0; i < 4; ++i)
            stage16(ga + (size_t)(i * 8) * C_ + k0, lA + (w * 32 + i * 8) * 64);
#pragma unroll
        for (int i = 0; i < 8; ++i)
            stage16(gb + (size_t)(i * 8) * C_ + k0, lB + (w * 64 + i * 8) * 64);
        __syncthreads();
#pragma unroll
        for (int ks = 0; ks < 2; ++ks) {
            int p = (ks * 4 + quad) ^ (l16 & 7);
            bf16x8 am[4], bn[8];
#pragma unroll
            for (int f = 0; f < 4; ++f)
                am[f] = *(const bf16x8*)&lA[(wm * 64 + f * 16 + l16) * 64 + p * 8];
#pragma unroll
            for (int f = 0; f < 8; ++f)
                bn[f] = *(const bf16x8*)&lB[(wn * 128 + f * 16 + l16) * 64 + p * 8];
#pragma unroll
            for (int fm = 0; fm < 4; ++fm)
#pragma unroll
                for (int fn = 0; fn < 8; ++fn)
                    acc[fm][fn] = mfma16(am[fm], bn[fn], acc[fm][fn]);
        }
    }
    // bias + residual into acc
    const bf16* xb = xa + ((size_t)pair * L_ + m0 + wm * 64) * C_;
#pragma unroll
    for (int fn = 0; fn < 8; ++fn) {
        int col = wn * 128 + fn * 16 + l16;
        float bias = bout[a * C_ + col];
#pragma unroll
        for (int fm = 0; fm < 4; ++fm)
#pragma unroll
            for (int r = 0; r < 4; ++r)
                acc[fm][fn][r] += bias + (float)xb[(size_t)(fm * 16 + quad * 4 + r) * C_ + col];
    }
    // per-wave partial row sums -> LDS
#pragma unroll
    for (int fm = 0; fm < 4; ++fm) {
#pragma unroll
        for (int r = 0; r < 4; ++r) {
            float s1 = 0.f, s2 = 0.f;
#pragma unroll
            for (int fn = 0; fn < 8; ++fn) {
                float v = acc[fm][fn][r];
                s1 += v; s2 += v * v;
            }
#pragma unroll
            for (int off = 1; off < 16; off <<= 1) {
                s1 += __shfl_xor(s1, off);
                s2 += __shfl_xor(s2, off);
            }
            if (l16 == 0) {
                int rl = fm * 16 + quad * 4 + r;
                red[wm][wn][rl][0] = s1;
                red[wm][wn][rl][1] = s2;
            }
        }
    }
    __syncthreads();
    bf16* yb = y + ((size_t)pair * L_ + m0 + wm * 64) * C_;
#pragma unroll
    for (int fm = 0; fm < 4; ++fm) {
#pragma unroll
        for (int r = 0; r < 4; ++r) {
            int rl = fm * 16 + quad * 4 + r;
            float t1 = red[wm][0][rl][0] + red[wm][1][rl][0];
            float t2 = red[wm][0][rl][1] + red[wm][1][rl][1];
            float mu = t1 * (1.f / 256.f);
            float var = t2 * (1.f / 256.f) - mu * mu;
            float rstd = rsqrtf(var + 1e-5f);
#pragma unroll
            for (int fn = 0; fn < 8; ++fn) {
                int col = wn * 128 + fn * 16 + l16;
                yb[(size_t)rl * C_ + col] =
                    (bf16)((acc[fm][fn][r] - mu) * rstd * gamma[col] + beta[col]);
            }
        }
    }
}

// ---------------------------------------------------------------------------
// K4: y[pair, l, c] (bf16) -> out[B,C,H,W] (f32)
// ---------------------------------------------------------------------------
__global__ __launch_bounds__(256) void k_merge(const bf16* __restrict__ y,
                                               float* __restrict__ out) {
    __shared__ float lds[32][257];
    int bid = blockIdx.x;
    int pair = bid >> 5, p = bid & 31;
    int b = pair >> 2, a = pair & 3, i = a >> 1, j = a & 1;
    int t = threadIdx.x;
    int q = t & 31, csub = t >> 5;
    const bf16* yr = y + ((size_t)pair * L_ + (size_t)p * 32) * C_;
    for (int r = 0; r < 32; ++r) {
        lds[r][t] = (float)yr[(size_t)r * C_ + t];
    }
    __syncthreads();
    float* xb = out + (size_t)b * C_ * H_ * W_ + (size_t)(i * 32 + p) * W_ + j * 32;
    for (int r = 0; r < 32; ++r) {
        int c = r * 8 + csub;
        xb[(size_t)c * H_ * W_ + q] = lds[q][c];
    }
}

// ---------------------------------------------------------------------------
extern "C" void kernel_launch(void* const* d_in, const int* in_sizes, int n_in,
                              void* d_out, int out_size, void* d_ws, size_t ws_size,
                              hipStream_t stream) {
    (void)in_sizes; (void)n_in; (void)out_size; (void)ws_size;
    const float* x     = (const float*)d_in[0];
    const float* Win   = (const float*)d_in[1];
    const float* bin   = (const float*)d_in[2];
    const float* Wout  = (const float*)d_in[3];
    const float* bout  = (const float*)d_in[4];
    const float* gamma = (const float*)d_in[5];
    const float* beta  = (const float*)d_in[6];
    float* out = (float*)d_out;

    char* ws = (char*)d_ws;
    bf16* xa    = (bf16*)ws;                           // 16 MiB
    bf16* qk    = (bf16*)(ws + ((size_t)16 << 20));    // 32 MiB  [pair][L][512]
    bf16* vT    = (bf16*)(ws + ((size_t)48 << 20));    // 16 MiB  [pair][256][1024]
    bf16* o     = (bf16*)(ws + ((size_t)64 << 20));    // 16 MiB
    bf16* Winb  = (bf16*)(ws + ((size_t)80 << 20));    // 1.5 MiB
    bf16* Woutb = (bf16*)(ws + ((size_t)82 << 20));    // 0.5 MiB
    bf16* y     = (bf16*)(ws + ((size_t)16 << 20));    // 16 MiB, aliases dead qk

    k_split<<<NPAIR * 32 + 1024, 256, 0, stream>>>(x, xa, Win, Wout, Winb, Woutb);
    k_qkv<<<NPAIR * 8 * 6, 256, 0, stream>>>(xa, Winb, bin, qk, vT);
    k_attn<<<NPAIR * NH_ * 4, 256, 0, stream>>>(qk, vT, o);
    k_out<<<NPAIR * 8, 256, 0, stream>>>(o, Woutb, bout, xa, gamma, beta, y);
    k_merge<<<NPAIR * 32, 256, 0, stream>>>(y, out);
}